// Round 9
// baseline (1272.557 us; speedup 1.0000x reference)
//
#include <hip/hip_runtime.h>

#define NPIX 262144   // B*H*H = 4*256*256
#define M1C 4096
#define M2C 512
#define E1C 65536
#define E2C 8192
#define NBLK 512      // persistent grid: 2 blocks/CU on 256 CUs -> co-resident
#define NA 128        // group-A blocks (level-2 tail)
#define MROWS 4       // rows per block-iteration in fused MLP phases
#define TOTW (NPIX + M1C + E1C + E2C)

// ---- workspace layout (4-byte element offsets) ----
// zeroed region: barrier go-words + flag arrays + int histograms:
constexpr int IOFF_GO   = 0;                       // global-barrier go word (own 128B line)
constexpr int IOFF_GO2  = 32;                      // group-A go word
constexpr int IOFF_FLG  = 64;                      // NBLK flags, stride 32 ints (128B)
constexpr int IOFF_FLG2 = IOFF_FLG + NBLK*32;      // NA flags, stride 32
constexpr int IOFF_H1   = IOFF_FLG2 + NA*32;       // 4096
constexpr int IOFF_HC2  = IOFF_H1  + M1C;          // 512
constexpr int IOFF_HE1  = IOFF_HC2 + M2C;          // 4096
constexpr int IOFF_HE2  = IOFF_HE1 + M1C;          // 512
constexpr int ZEROI_END = IOFF_HE2 + M2C;

constexpr int IOFF_ST1   = ZEROI_END;              // 4097
constexpr int IOFF_CU1   = IOFF_ST1  + M1C + 1;    // 4096
constexpr int IOFF_STC2  = IOFF_CU1  + M1C;        // 513
constexpr int IOFF_CUC2  = IOFF_STC2 + M2C + 1;    // 512
constexpr int IOFF_STE1  = IOFF_CUC2 + M2C;        // 4097
constexpr int IOFF_CUE1  = IOFF_STE1 + M1C + 1;    // 4096
constexpr int IOFF_STE2  = IOFF_CUE1 + M1C;        // 513
constexpr int IOFF_CUE2  = IOFF_STE2 + M2C + 1;    // 512
constexpr int IOFF_PLIST = IOFF_CUE2 + M2C;        // 262144 (pixels sorted by cluster)
constexpr int IOFF_R2L   = IOFF_PLIST + NPIX;      // 4096
constexpr int IOFF_E1L   = IOFF_R2L + M1C;         // 65536
constexpr int IOFF_E2L   = IOFF_E1L + E1C;         // 8192
constexpr int IEND0      = IOFF_E2L + E2C;
constexpr int IEND       = (IEND0 + 3) & ~3;       // 16B-align the float region

// float scratch:
constexpr int OFF_S1CR  = IEND;                    // 4096*4 raw coord sums
constexpr int OFF_C1    = OFF_S1CR + M1C*4;        // 4096 counts
constexpr int OFF_X1CAT = OFF_C1 + M1C;            // 4096*68
constexpr int OFF_X1FC  = OFF_X1CAT + M1C*68;      // 4096*64
constexpr int OFF_X1    = OFF_X1FC + M1C*64;       // 4096*64
constexpr int OFF_X2CAT = OFF_X1 + M1C*64;         // 512*68
constexpr int OFF_X2FC  = OFF_X2CAT + M2C*68;      // 512*64
constexpr int OFF_X2    = OFF_X2FC + M2C*64;       // 512*64
constexpr int OFF_JSF1  = OFF_X2 + M2C*64;         // 4096*20
constexpr int OFF_JSF2  = OFF_JSF1 + M1C*20;       // 512*20

// ---------------- flag-array device barrier: store-arrival, root-aggregate, go-broadcast ----------------
// No RMW anywhere. Each block release-stores its own padded flag; block `rootbid` polls
// all flags (256 threads, distinct lines), then release-stores `go`; others spin on `go`.
// Monotonic phase numbers -> no reset race.
__device__ __forceinline__ void flagbar(int* flags, int* go, int nblk, int phase,
                                        int bid, int rootbid, int tid) {
  __syncthreads();
  __threadfence();
  if (tid == 0)
    __hip_atomic_store(flags + (size_t)bid*32, phase, __ATOMIC_RELEASE, __HIP_MEMORY_SCOPE_AGENT);
  if (bid == rootbid) {
    for (;;) {
      int ok = 1;
      for (int i = tid; i < nblk; i += 256)
        if (__hip_atomic_load(flags + (size_t)i*32, __ATOMIC_ACQUIRE, __HIP_MEMORY_SCOPE_AGENT) < phase)
          ok = 0;
      if (__syncthreads_and(ok)) break;
      __builtin_amdgcn_s_sleep(2);
    }
    if (tid == 0)
      __hip_atomic_store(go, phase, __ATOMIC_RELEASE, __HIP_MEMORY_SCOPE_AGENT);
  }
  if (tid == 0) {
    while (__hip_atomic_load(go, __ATOMIC_ACQUIRE, __HIP_MEMORY_SCOPE_AGENT) < phase)
      __builtin_amdgcn_s_sleep(2);
  }
  __syncthreads();
  __threadfence();
}

// ---------------- 256-thread exclusive scan of N bins ----------------
template<int N>
__device__ __forceinline__ void scan256(const int* __restrict__ hist, int* __restrict__ start,
                                        int* __restrict__ curs, int* part, int tid) {
  constexpr int IT = N / 256;
  int base = tid * IT;
  int loc[IT];
  int sum = 0;
  #pragma unroll
  for (int k = 0; k < IT; ++k) { loc[k] = sum; sum += hist[base + k]; }
  part[tid] = sum;
  __syncthreads();
  for (int off = 1; off < 256; off <<= 1) {
    int v = (tid >= off) ? part[tid - off] : 0;
    __syncthreads();
    part[tid] += v;
    __syncthreads();
  }
  int excl = tid ? part[tid - 1] : 0;
  #pragma unroll
  for (int k = 0; k < IT; ++k) { start[base+k] = excl + loc[k]; curs[base+k] = excl + loc[k]; }
  if (tid == 255) start[N] = part[255];
  __syncthreads();
}

// ---------------- block-level dense layer (latency-optimized, LDS activations) ----------------
template<int NIN, int NOUT, int R, bool RELU>
__device__ __forceinline__ void block_layer(
    const float* __restrict__ W, const float* __restrict__ B,
    const float* __restrict__ actIn, float* __restrict__ actOut, int tid) {
  constexpr int NG  = 256 / NOUT;
  constexpr int RPT = (R + NG - 1) / NG;
  static_assert(NIN % 4 == 0, "NIN must be multiple of 4");
  int c  = tid % NOUT;
  int rg = tid / NOUT;
  if (rg < NG) {
    float acc[RPT];
    #pragma unroll
    for (int i = 0; i < RPT; ++i) acc[i] = 0.f;
    #pragma unroll 4
    for (int kc = 0; kc < NIN/4; ++kc) {
      float w0 = W[(kc*4+0)*NOUT + c];
      float w1 = W[(kc*4+1)*NOUT + c];
      float w2 = W[(kc*4+2)*NOUT + c];
      float w3 = W[(kc*4+3)*NOUT + c];
      #pragma unroll
      for (int i = 0; i < RPT; ++i) {
        int r = rg + i*NG;
        if (r < R) {
          float4 a = *reinterpret_cast<const float4*>(actIn + r*NIN + kc*4);
          acc[i] = fmaf(a.x, w0, fmaf(a.y, w1, fmaf(a.z, w2, fmaf(a.w, w3, acc[i]))));
        }
      }
    }
    float b = B[c];
    #pragma unroll
    for (int i = 0; i < RPT; ++i) {
      int r = rg + i*NG;
      if (r < R) {
        float v = acc[i] + b;
        actOut[r*NOUT + c] = RELU ? fmaxf(v, 0.f) : v;
      }
    }
  }
  __syncthreads();
}

// ---------------- t-MLP on 4 rows: 68 -> 100 -> 100 -> 100 -> 64 ----------------
__device__ __forceinline__ void mlp_t4(
    const float* __restrict__ X, const float* wi, const float* bi,
    const float* wh, const float* bh, const float* wo, const float* bo,
    float* __restrict__ Y, int r0, float* bufA, float* bufB, int tid) {
  for (int o = tid; o < MROWS*68; o += 256) bufA[o] = X[r0*68 + o];
  __syncthreads();
  block_layer<68,100,MROWS,true>(wi, bi, bufA, bufB, tid);
  block_layer<100,100,MROWS,true>(wh, bh, bufB, bufA, tid);
  block_layer<100,100,MROWS,true>(wh+10000, bh+100, bufA, bufB, tid);
  block_layer<100,64,MROWS,false>(wo, bo, bufB, bufA, tid);
  for (int o = tid; o < MROWS*64; o += 256) Y[r0*64 + o] = bufA[o];
  __syncthreads();
}

// ---------------- q-MLP on 4 rows: 64 -> 100^3 -> 18 (J stride 20) ----------------
__device__ __forceinline__ void mlp_q4(
    const float* __restrict__ X, const float* wi, const float* bi,
    const float* wh, const float* bh, const float* wo, const float* bo,
    float* __restrict__ J, int r0, float* bufA, float* bufB, int tid) {
  for (int o = tid; o < MROWS*64; o += 256) bufA[o] = X[r0*64 + o];
  __syncthreads();
  block_layer<64,100,MROWS,true>(wi, bi, bufA, bufB, tid);
  block_layer<100,100,MROWS,true>(wh, bh, bufB, bufA, tid);
  block_layer<100,100,MROWS,true>(wh+10000, bh+100, bufA, bufB, tid);
  block_layer<100,18,MROWS,false>(wo, bo, bufB, bufA, tid);
  for (int o = tid; o < MROWS*18; o += 256) {
    int r = o / 18, c = o - r*18;
    J[(r0+r)*20 + c] = bufA[o];
  }
  __syncthreads();
}

// ---------------- graph conv for one dst row, one wave ----------------
__device__ __forceinline__ void gc_wave(
    const int* __restrict__ start, const int* __restrict__ elist, const float* __restrict__ xin,
    const float* wn, const float* wsf, const float* bias,
    float* __restrict__ xout, float* __restrict__ out_f, int d, int c, float* sm) {
  int p0 = start[d], p1 = start[d+1];
  float acc = 0.f;
  for (int p = p0; p < p1; ++p) acc += xin[elist[p]*64 + c];
  sm[c]      = acc / fmaxf((float)(p1 - p0), 1.0f);
  sm[64 + c] = xin[d*64 + c];
  __syncthreads();
  float o = bias[c];
  #pragma unroll 8
  for (int k = 0; k < 64; ++k)
    o += sm[k]*wn[k*64 + c] + sm[64 + k]*wsf[k*64 + c];
  xout[d*64 + c] = o;
  out_f[d*64 + c] = o;
  __syncthreads();
}

// ==================== the persistent mega-kernel ====================
__global__ __launch_bounds__(256, 2) void mega(
    const float* __restrict__ img, const float* __restrict__ cw, const float* __restrict__ cb,
    const float* t1_wi, const float* t1_bi, const float* t1_wh, const float* t1_bh,
    const float* t1_wo, const float* t1_bo,
    const float* t2_wi, const float* t2_bi, const float* t2_wh, const float* t2_bh,
    const float* t2_wo, const float* t2_bo,
    const float* q_wi, const float* q_bi, const float* q_wh, const float* q_bh,
    const float* q_wo, const float* q_bo,
    const float* gc1_wn, const float* gc1_ws, const float* gc1_b,
    const float* gc2_wn, const float* gc2_ws, const float* gc2_b,
    const int* __restrict__ cluster1, const int* __restrict__ cluster2,
    const int* __restrict__ e1, const int* __restrict__ e2,
    float* __restrict__ ws, float* __restrict__ o_r1, float* __restrict__ o_r2,
    float* __restrict__ o_x1, float* __restrict__ o_x2) {
  int* wsI  = (int*)ws;
  int* go   = wsI + IOFF_GO;
  int* go2  = wsI + IOFF_GO2;
  int* flg  = wsI + IOFF_FLG;
  int* flg2 = wsI + IOFF_FLG2;
  int bid = blockIdx.x, tid = threadIdx.x;
  int gid = bid*256 + tid;
  int wv = tid >> 6, l = tid & 63;
  int wid = bid*4 + wv;                       // global wave id, 2048 waves

  __shared__ __align__(16) float bufA[MROWS*100];
  __shared__ __align__(16) float bufB[MROWS*100];
  __shared__ float smW[4*128];
  __shared__ int  part[256];

  // ---- P1: histograms ----
  for (int i = gid; i < TOTW; i += NBLK*256) {
    if (i < NPIX) {
      atomicAdd(&wsI[IOFF_H1 + cluster1[i]], 1);
    } else if (i < NPIX + M1C) {
      atomicAdd(&wsI[IOFF_HC2 + cluster2[i - NPIX]], 1);
    } else if (i < NPIX + M1C + E1C) {
      int e = i - NPIX - M1C;
      atomicAdd(&wsI[IOFF_HE1 + e1[E1C + e]], 1);
    } else {
      int e = i - NPIX - M1C - E1C;
      atomicAdd(&wsI[IOFF_HE2 + e2[E2C + e]], 1);
    }
  }
  flagbar(flg, go, NBLK, 1, bid, 0, tid);

  // ---- P2: exclusive scans (blocks 0..3) ----
  if (bid == 0)      scan256<M1C>(wsI+IOFF_H1,  wsI+IOFF_ST1,  wsI+IOFF_CU1,  part, tid);
  else if (bid == 1) scan256<M2C>(wsI+IOFF_HC2, wsI+IOFF_STC2, wsI+IOFF_CUC2, part, tid);
  else if (bid == 2) scan256<M1C>(wsI+IOFF_HE1, wsI+IOFF_STE1, wsI+IOFF_CUE1, part, tid);
  else if (bid == 3) scan256<M2C>(wsI+IOFF_HE2, wsI+IOFF_STE2, wsI+IOFF_CUE2, part, tid);
  flagbar(flg, go, NBLK, 2, bid, 0, tid);

  // ---- P3: scatter into bins ----
  for (int i = gid; i < TOTW; i += NBLK*256) {
    if (i < NPIX) {
      int s = cluster1[i];
      int pos = atomicAdd(&wsI[IOFF_CU1 + s], 1);
      wsI[IOFF_PLIST + pos] = i;
    } else if (i < NPIX + M1C) {
      int r = i - NPIX;
      int pos = atomicAdd(&wsI[IOFF_CUC2 + cluster2[r]], 1);
      wsI[IOFF_R2L + pos] = r;
    } else if (i < NPIX + M1C + E1C) {
      int e = i - NPIX - M1C;
      int pos = atomicAdd(&wsI[IOFF_CUE1 + e1[E1C + e]], 1);
      wsI[IOFF_E1L + pos] = e1[e];
    } else {
      int e = i - NPIX - M1C - E1C;
      int pos = atomicAdd(&wsI[IOFF_CUE2 + e2[E2C + e]], 1);
      wsI[IOFF_E2L + pos] = e2[e];
    }
  }
  flagbar(flg, go, NBLK, 3, bid, 0, tid);

  // ---- P4: conv-linearity cluster gather (wave per cluster, 2 clusters/wave) ----
  {
    const int* startp = wsI + IOFF_ST1;
    const int* plist  = wsI + IOFF_PLIST;
    for (int s = wid; s < M1C; s += 2048) {
      int p0 = startp[s], p1 = startp[s+1];
      int count = p1 - p0;
      float ps[27];
      #pragma unroll
      for (int k = 0; k < 27; ++k) ps[k] = 0.f;
      float sy = 0.f, sx = 0.f, syy = 0.f, sxx = 0.f;
      for (int p = p0 + l; p < p1; p += 64) {
        int n = plist[p];
        int b = n >> 16, pp = n & 65535, i = pp >> 8, j = pp & 255;
        #pragma unroll
        for (int di = 0; di < 3; ++di) {
          int y = i + di - 1;
          #pragma unroll
          for (int dj = 0; dj < 3; ++dj) {
            int x = j + dj - 1;
            int k = (di*3 + dj)*3;
            if ((unsigned)y < 256u && (unsigned)x < 256u) {
              int base = ((b << 16) + (y << 8) + x) * 3;
              ps[k+0] += img[base];
              ps[k+1] += img[base+1];
              ps[k+2] += img[base+2];
            }
          }
        }
        float yi = i * (1.0f/256.0f), xj = j * (1.0f/256.0f);
        sy += yi; sx += xj; syy += yi*yi; sxx += xj*xj;
      }
      #pragma unroll
      for (int m = 1; m < 64; m <<= 1) {
        #pragma unroll
        for (int k = 0; k < 27; ++k) ps[k] += __shfl_xor(ps[k], m);
        sy  += __shfl_xor(sy,  m);
        sx  += __shfl_xor(sx,  m);
        syy += __shfl_xor(syy, m);
        sxx += __shfl_xor(sxx, m);
      }
      float inv = 1.0f / fmaxf((float)count, 1.0f);
      float o = cb[l];
      #pragma unroll
      for (int k = 0; k < 27; ++k) o = fmaf(ps[k]*inv, cw[k*64 + l], o);
      ws[OFF_X1CAT + s*68 + l] = count ? o : 0.f;
      if (l == 0) {
        ws[OFF_X1CAT + s*68 + 64] = sy*inv;
        ws[OFF_X1CAT + s*68 + 65] = sx*inv;
        ws[OFF_X1CAT + s*68 + 66] = syy*inv;
        ws[OFF_X1CAT + s*68 + 67] = sxx*inv;
        ws[OFF_S1CR + s*4+0] = sy; ws[OFF_S1CR + s*4+1] = sx;
        ws[OFF_S1CR + s*4+2] = syy; ws[OFF_S1CR + s*4+3] = sxx;
        ws[OFF_JSF1 + s*20 + 18] = sy*inv;
        ws[OFF_JSF1 + s*20 + 19] = sx*inv;
        ws[OFF_C1 + s] = (float)count;
      }
    }
  }
  flagbar(flg, go, NBLK, 4, bid, 0, tid);

  // ---- P5: t1 MLP (1024 row-blocks over 512 blocks) ----
  for (int rb = bid; rb < M1C/MROWS; rb += NBLK)
    mlp_t4(ws+OFF_X1CAT, t1_wi, t1_bi, t1_wh, t1_bh, t1_wo, t1_bo,
           ws+OFF_X1FC, rb*MROWS, bufA, bufB, tid);
  flagbar(flg, go, NBLK, 5, bid, 0, tid);

  // ---- P6: graph conv 1 (wave per dst, 2 dst/wave) ----
  for (int d = wid; d < M1C; d += 2048)
    gc_wave(wsI+IOFF_STE1, wsI+IOFF_E1L, ws+OFF_X1FC,
            gc1_wn, gc1_ws, gc1_b, ws+OFF_X1, o_x1, d, l, smW + wv*128);
  flagbar(flg, go, NBLK, 6, bid, 0, tid);

  // ---- split: group A (bid<NA) does the level-2 tail; group B does q-MLP on x1 ----
  if (bid < NA) {
    // A1: pool_l2 (wave per cluster, 512 waves exact)
    {
      int s2 = wid;                               // wid < 512 for bid < 128
      const int* startc2 = wsI + IOFF_STC2;
      const int* r2list  = wsI + IOFF_R2L;
      int p0 = startc2[s2], p1 = startc2[s2+1];
      int k = l & 3;
      float acc = 0.f, sc = 0.f, cnt = 0.f;
      for (int p = p0; p < p1; ++p) {
        int r = r2list[p];
        acc += ws[OFF_X1 + r*64 + l];
        sc  += ws[OFF_S1CR + r*4 + k];
        cnt += ws[OFF_C1 + r];
      }
      float invr = 1.0f / fmaxf((float)(p1 - p0), 1.0f);
      ws[OFF_X2CAT + s2*68 + l] = acc * invr;
      if (l < 4) {
        float mean = sc / fmaxf(cnt, 1.0f);
        ws[OFF_X2CAT + s2*68 + 64 + l] = mean;
        if (l == 0) ws[OFF_JSF2 + s2*20 + 18] = mean;
        if (l == 1) ws[OFF_JSF2 + s2*20 + 19] = mean;
      }
    }
    flagbar(flg2, go2, NA, 1, bid, 0, tid);
    // A2: t2 MLP (128 row-blocks exact)
    mlp_t4(ws+OFF_X2CAT, t2_wi, t2_bi, t2_wh, t2_bh, t2_wo, t2_bo,
           ws+OFF_X2FC, bid*MROWS, bufA, bufB, tid);
    flagbar(flg2, go2, NA, 2, bid, 0, tid);
    // A3: graph conv 2 (512 waves exact)
    gc_wave(wsI+IOFF_STE2, wsI+IOFF_E2L, ws+OFF_X2FC,
            gc2_wn, gc2_ws, gc2_b, ws+OFF_X2, o_x2, wid, l, smW + wv*128);
    flagbar(flg2, go2, NA, 3, bid, 0, tid);
    // A4: q MLP on x2 rows (128 row-blocks exact)
    mlp_q4(ws+OFF_X2, q_wi, q_bi, q_wh, q_bh, q_wo, q_bo,
           ws+OFF_JSF2, bid*MROWS, bufA, bufB, tid);
  } else {
    // B: q MLP on x1 rows (1024 row-blocks over 384 blocks)
    for (int rb = bid - NA; rb < M1C/MROWS; rb += (NBLK - NA))
      mlp_q4(ws+OFF_X1, q_wi, q_bi, q_wh, q_bh, q_wo, q_bo,
             ws+OFF_JSF1, rb*MROWS, bufA, bufB, tid);
  }
  flagbar(flg, go, NBLK, 7, bid, 0, tid);

  // ---- P8: render ----
  for (int n = gid; n < NPIX; n += NBLK*256) {
    int p = n & 65535, i = p >> 8, j = p & 255;
    float gy = i * (1.0f/256.0f), gx = j * (1.0f/256.0f);
    int s = cluster1[n];
    {
      const float4* f4 = reinterpret_cast<const float4*>(ws + OFF_JSF1 + s*20);
      float4 v0 = f4[0], v1 = f4[1], v2 = f4[2], v3 = f4[3], v4 = f4[4];
      float dx = gy - v0.x, dy = gx - v0.y;
      float dxx = dx*dx, dyy = dy*dy, dxy = dx*dy;
      o_r1[n*3 + 0] = v0.z + v0.w*dx + v1.x*dy + v1.y*dxx + v1.z*dyy + v1.w*dxy;
      o_r1[n*3 + 1] = v2.x + v2.y*dx + v2.z*dy + v2.w*dxx + v3.x*dyy + v3.y*dxy;
      o_r1[n*3 + 2] = v3.z + v3.w*dx + v4.x*dy + v4.y*dxx + v4.z*dyy + v4.w*dxy;
    }
    int s2 = cluster2[s];
    {
      const float4* f4 = reinterpret_cast<const float4*>(ws + OFF_JSF2 + s2*20);
      float4 v0 = f4[0], v1 = f4[1], v2 = f4[2], v3 = f4[3], v4 = f4[4];
      float dx = gy - v0.x, dy = gx - v0.y;
      float dxx = dx*dx, dyy = dy*dy, dxy = dx*dy;
      o_r2[n*3 + 0] = v0.z + v0.w*dx + v1.x*dy + v1.y*dxx + v1.z*dyy + v1.w*dxy;
      o_r2[n*3 + 1] = v2.x + v2.y*dx + v2.z*dy + v2.w*dxx + v3.x*dyy + v3.y*dxy;
      o_r2[n*3 + 2] = v3.z + v3.w*dx + v4.x*dy + v4.y*dxx + v4.z*dyy + v4.w*dxy;
    }
  }
}

extern "C" void kernel_launch(void* const* d_in, const int* in_sizes, int n_in,
                              void* d_out, int out_size, void* d_ws, size_t ws_size,
                              hipStream_t stream) {
  const float* img    = (const float*)d_in[0];
  const float* conv_w = (const float*)d_in[1];
  const float* conv_b = (const float*)d_in[2];
  const float* t1_wi = (const float*)d_in[3];  const float* t1_bi = (const float*)d_in[4];
  const float* t1_wh = (const float*)d_in[5];  const float* t1_bh = (const float*)d_in[6];
  const float* t1_wo = (const float*)d_in[7];  const float* t1_bo = (const float*)d_in[8];
  const float* t2_wi = (const float*)d_in[9];  const float* t2_bi = (const float*)d_in[10];
  const float* t2_wh = (const float*)d_in[11]; const float* t2_bh = (const float*)d_in[12];
  const float* t2_wo = (const float*)d_in[13]; const float* t2_bo = (const float*)d_in[14];
  const float* q_wi  = (const float*)d_in[15]; const float* q_bi  = (const float*)d_in[16];
  const float* q_wh  = (const float*)d_in[17]; const float* q_bh  = (const float*)d_in[18];
  const float* q_wo  = (const float*)d_in[19]; const float* q_bo  = (const float*)d_in[20];
  const float* gc1_wn = (const float*)d_in[21]; const float* gc1_ws = (const float*)d_in[22];
  const float* gc1_b  = (const float*)d_in[23];
  const float* gc2_wn = (const float*)d_in[24]; const float* gc2_ws = (const float*)d_in[25];
  const float* gc2_b  = (const float*)d_in[26];
  const int* cluster1 = (const int*)d_in[27];
  const int* cluster2 = (const int*)d_in[28];
  const int* edges1   = (const int*)d_in[29];
  const int* edges2   = (const int*)d_in[30];

  float* ws = (float*)d_ws;
  float* out  = (float*)d_out;
  float* o_r1 = out;
  float* o_r2 = out + 786432;
  float* o_x1 = out + 1572864;
  float* o_x2 = out + 1835008;

  // zero go-words + flag arrays + int histograms (~120 KB)
  hipMemsetAsync(d_ws, 0, (size_t)ZEROI_END * sizeof(int), stream);

  mega<<<NBLK, 256, 0, stream>>>(
      img, conv_w, conv_b,
      t1_wi, t1_bi, t1_wh, t1_bh, t1_wo, t1_bo,
      t2_wi, t2_bi, t2_wh, t2_bh, t2_wo, t2_bo,
      q_wi, q_bi, q_wh, q_bh, q_wo, q_bo,
      gc1_wn, gc1_ws, gc1_b, gc2_wn, gc2_ws, gc2_b,
      cluster1, cluster2, edges1, edges2,
      ws, o_r1, o_r2, o_x1, o_x2);
}

// Round 10
// 180.337 us; speedup vs baseline: 7.0566x; 7.0566x over previous
//
#include <hip/hip_runtime.h>

#define NPIX 262144   // B*H*H = 4*256*256
#define M1C 4096
#define M2C 512
#define E1C 65536
#define E2C 8192

// ---- workspace layout (4-byte element offsets) ----
// zeroed region (int histograms only):
constexpr int IOFF_H1   = 0;                 // 4096
constexpr int IOFF_HC2  = IOFF_H1  + M1C;    // 512
constexpr int IOFF_HE1  = IOFF_HC2 + M2C;    // 4096
constexpr int IOFF_HE2  = IOFF_HE1 + M1C;    // 512
constexpr int ZEROI_END = IOFF_HE2 + M2C;    // 9216 ints

constexpr int IOFF_ST1   = ZEROI_END;              // 4097
constexpr int IOFF_CU1   = IOFF_ST1  + M1C + 1;    // 4096
constexpr int IOFF_STC2  = IOFF_CU1  + M1C;        // 513
constexpr int IOFF_CUC2  = IOFF_STC2 + M2C + 1;    // 512
constexpr int IOFF_STE1  = IOFF_CUC2 + M2C;        // 4097
constexpr int IOFF_CUE1  = IOFF_STE1 + M1C + 1;    // 4096
constexpr int IOFF_STE2  = IOFF_CUE1 + M1C;        // 513
constexpr int IOFF_CUE2  = IOFF_STE2 + M2C + 1;    // 512
constexpr int IOFF_PLIST = IOFF_CUE2 + M2C;        // 262144 (pixels sorted by cluster)
constexpr int IOFF_R2L   = IOFF_PLIST + NPIX;      // 4096
constexpr int IOFF_E1L   = IOFF_R2L + M1C;         // 65536
constexpr int IOFF_E2L   = IOFF_E1L + E1C;         // 8192
constexpr int IEND0      = IOFF_E2L + E2C;
constexpr int IEND       = (IEND0 + 3) & ~3;       // 16B-align float region

// float scratch:
constexpr int OFF_S1CR  = IEND;                    // 4096*4 raw coord sums
constexpr int OFF_C1    = OFF_S1CR + M1C*4;        // 4096 counts
constexpr int OFF_X1FC  = OFF_C1 + M1C;            // 4096*64 (t1 out, gc1 in)
constexpr int OFF_X1    = OFF_X1FC + M1C*64;       // 4096*64 (gc1 out, pool in)
constexpr int OFF_X2FC  = OFF_X1 + M1C*64;         // 512*64  (t2 out, gc2 in)
constexpr int OFF_JSF1  = OFF_X2FC + M2C*64;       // 4096*20 (80B rows, 16B-aligned)
constexpr int OFF_JSF2  = OFF_JSF1 + M1C*20;       // 512*20

// ---------------- fused histograms ----------------
__global__ __launch_bounds__(256) void build_hist(
    const int* __restrict__ c1, const int* __restrict__ c2,
    const int* __restrict__ e1, const int* __restrict__ e2, int* __restrict__ wsI) {
  int i = blockIdx.x*256 + threadIdx.x;
  if (i < NPIX) {
    atomicAdd(&wsI[IOFF_H1 + c1[i]], 1);
  } else if (i < NPIX + M1C) {
    atomicAdd(&wsI[IOFF_HC2 + c2[i - NPIX]], 1);
  } else if (i < NPIX + M1C + E1C) {
    int e = i - NPIX - M1C;
    atomicAdd(&wsI[IOFF_HE1 + e1[E1C + e]], 1);
  } else {
    int e = i - NPIX - M1C - E1C;
    atomicAdd(&wsI[IOFF_HE2 + e2[E2C + e]], 1);
  }
}

// ---------------- exclusive scan, one block per histogram ----------------
__global__ __launch_bounds__(1024) void scan_kernel(int* __restrict__ wsI) {
  const int* hist; int* start; int* curs; int n;
  if (blockIdx.x == 0)      { hist = wsI+IOFF_H1;  start = wsI+IOFF_ST1;  curs = wsI+IOFF_CU1;  n = M1C; }
  else if (blockIdx.x == 1) { hist = wsI+IOFF_HC2; start = wsI+IOFF_STC2; curs = wsI+IOFF_CUC2; n = M2C; }
  else if (blockIdx.x == 2) { hist = wsI+IOFF_HE1; start = wsI+IOFF_STE1; curs = wsI+IOFF_CUE1; n = M1C; }
  else                      { hist = wsI+IOFF_HE2; start = wsI+IOFF_STE2; curs = wsI+IOFF_CUE2; n = M2C; }
  __shared__ int part[1024];
  int t = threadIdx.x, base = t*4, sum = 0;
  int loc0, loc1, loc2, loc3;
  loc0 = sum; sum += (base+0 < n) ? hist[base+0] : 0;
  loc1 = sum; sum += (base+1 < n) ? hist[base+1] : 0;
  loc2 = sum; sum += (base+2 < n) ? hist[base+2] : 0;
  loc3 = sum; sum += (base+3 < n) ? hist[base+3] : 0;
  part[t] = sum;
  __syncthreads();
  for (int off = 1; off < 1024; off <<= 1) {
    int v = (t >= off) ? part[t-off] : 0;
    __syncthreads();
    part[t] += v;
    __syncthreads();
  }
  int excl = (t == 0) ? 0 : part[t-1];
  if (base+0 < n) { start[base+0] = excl+loc0; curs[base+0] = excl+loc0; }
  if (base+1 < n) { start[base+1] = excl+loc1; curs[base+1] = excl+loc1; }
  if (base+2 < n) { start[base+2] = excl+loc2; curs[base+2] = excl+loc2; }
  if (base+3 < n) { start[base+3] = excl+loc3; curs[base+3] = excl+loc3; }
  if (t == 0) start[n] = part[1023];
}

// ---------------- fused scatter into bins ----------------
__global__ __launch_bounds__(256) void scatter_all(
    const int* __restrict__ c1, const int* __restrict__ c2,
    const int* __restrict__ e1, const int* __restrict__ e2, int* __restrict__ wsI) {
  int i = blockIdx.x*256 + threadIdx.x;
  if (i < NPIX) {
    int s = c1[i];
    int pos = atomicAdd(&wsI[IOFF_CU1 + s], 1);
    wsI[IOFF_PLIST + pos] = i;
  } else if (i < NPIX + M1C) {
    int r = i - NPIX;
    int pos = atomicAdd(&wsI[IOFF_CUC2 + c2[r]], 1);
    wsI[IOFF_R2L + pos] = r;
  } else if (i < NPIX + M1C + E1C) {
    int e = i - NPIX - M1C;
    int pos = atomicAdd(&wsI[IOFF_CUE1 + e1[E1C + e]], 1);
    wsI[IOFF_E1L + pos] = e1[e];
  } else {
    int e = i - NPIX - M1C - E1C;
    int pos = atomicAdd(&wsI[IOFF_CUE2 + e2[E2C + e]], 1);
    wsI[IOFF_E2L + pos] = e2[e];
  }
}

// ---------------- block-level dense layer (latency-optimized, LDS activations) ----------------
template<int NIN, int NOUT, int R, bool RELU>
__device__ __forceinline__ void block_layer(
    const float* __restrict__ W, const float* __restrict__ B,
    const float* __restrict__ actIn, float* __restrict__ actOut, int tid) {
  constexpr int NG  = 256 / NOUT;
  constexpr int RPT = (R + NG - 1) / NG;
  static_assert(NIN % 4 == 0, "NIN must be multiple of 4");
  int c  = tid % NOUT;
  int rg = tid / NOUT;
  if (rg < NG) {
    float acc[RPT];
    #pragma unroll
    for (int i = 0; i < RPT; ++i) acc[i] = 0.f;
    #pragma unroll 4
    for (int kc = 0; kc < NIN/4; ++kc) {
      float w0 = W[(kc*4+0)*NOUT + c];
      float w1 = W[(kc*4+1)*NOUT + c];
      float w2 = W[(kc*4+2)*NOUT + c];
      float w3 = W[(kc*4+3)*NOUT + c];
      #pragma unroll
      for (int i = 0; i < RPT; ++i) {
        int r = rg + i*NG;
        if (r < R) {
          float4 a = *reinterpret_cast<const float4*>(actIn + r*NIN + kc*4);
          acc[i] = fmaf(a.x, w0, fmaf(a.y, w1, fmaf(a.z, w2, fmaf(a.w, w3, acc[i]))));
        }
      }
    }
    float b = B[c];
    #pragma unroll
    for (int i = 0; i < RPT; ++i) {
      int r = rg + i*NG;
      if (r < R) {
        float v = acc[i] + b;
        actOut[r*NOUT + c] = RELU ? fmaxf(v, 0.f) : v;
      }
    }
  }
  __syncthreads();
}

// ==================== K1: conv-linearity gather + t1 MLP (4 clusters/block) ====================
__global__ __launch_bounds__(256) void k1_gather_t1(
    const float* __restrict__ img, const float* __restrict__ cw, const float* __restrict__ cb,
    const int* __restrict__ start, const int* __restrict__ plist,
    const float* t1_wi, const float* t1_bi, const float* t1_wh, const float* t1_bh,
    const float* t1_wo, const float* t1_bo,
    float* __restrict__ x1fc, float* __restrict__ s1c_raw, float* __restrict__ c1f,
    float* __restrict__ jsf1) {
  int tid = threadIdx.x, wv = tid >> 6, l = tid & 63;
  int s = blockIdx.x*4 + wv;
  __shared__ __align__(16) float bufA[4*100];
  __shared__ __align__(16) float bufB[4*100];
  // --- gather phase (wave per cluster) ---
  int p0 = start[s], p1 = start[s+1];
  int count = p1 - p0;
  float ps[27];
  #pragma unroll
  for (int k = 0; k < 27; ++k) ps[k] = 0.f;
  float sy = 0.f, sx = 0.f, syy = 0.f, sxx = 0.f;
  for (int p = p0 + l; p < p1; p += 64) {
    int n = plist[p];
    int b = n >> 16, pp = n & 65535, i = pp >> 8, j = pp & 255;
    #pragma unroll
    for (int di = 0; di < 3; ++di) {
      int y = i + di - 1;
      #pragma unroll
      for (int dj = 0; dj < 3; ++dj) {
        int x = j + dj - 1;
        int k = (di*3 + dj)*3;
        if ((unsigned)y < 256u && (unsigned)x < 256u) {
          int base = ((b << 16) + (y << 8) + x) * 3;
          ps[k+0] += img[base];
          ps[k+1] += img[base+1];
          ps[k+2] += img[base+2];
        }
      }
    }
    float yi = i * (1.0f/256.0f), xj = j * (1.0f/256.0f);
    sy += yi; sx += xj; syy += yi*yi; sxx += xj*xj;
  }
  #pragma unroll
  for (int m = 1; m < 64; m <<= 1) {
    #pragma unroll
    for (int k = 0; k < 27; ++k) ps[k] += __shfl_xor(ps[k], m);
    sy  += __shfl_xor(sy,  m);
    sx  += __shfl_xor(sx,  m);
    syy += __shfl_xor(syy, m);
    sxx += __shfl_xor(sxx, m);
  }
  float inv = 1.0f / fmaxf((float)count, 1.0f);
  float o = cb[l];
  #pragma unroll
  for (int k = 0; k < 27; ++k) o = fmaf(ps[k]*inv, cw[k*64 + l], o);
  bufA[wv*68 + l] = count ? o : 0.f;                // x1cat row lives in LDS only
  if (l == 0) {
    bufA[wv*68 + 64] = sy*inv;
    bufA[wv*68 + 65] = sx*inv;
    bufA[wv*68 + 66] = syy*inv;
    bufA[wv*68 + 67] = sxx*inv;
    s1c_raw[s*4+0] = sy; s1c_raw[s*4+1] = sx;
    s1c_raw[s*4+2] = syy; s1c_raw[s*4+3] = sxx;
    jsf1[s*20 + 18] = sy*inv;
    jsf1[s*20 + 19] = sx*inv;
    c1f[s] = (float)count;
  }
  __syncthreads();
  // --- t1 MLP on the block's 4 rows ---
  block_layer<68,100,4,true>(t1_wi, t1_bi, bufA, bufB, tid);
  block_layer<100,100,4,true>(t1_wh, t1_bh, bufB, bufA, tid);
  block_layer<100,100,4,true>(t1_wh+10000, t1_bh+100, bufA, bufB, tid);
  block_layer<100,64,4,false>(t1_wo, t1_bo, bufB, bufA, tid);
  int r0 = blockIdx.x*4;
  for (int o2 = tid; o2 < 4*64; o2 += 256) x1fc[r0*64 + o2] = bufA[o2];
}

// ==================== K2: gc1 + q-MLP(x1) (4 rows/block, 1024 blocks) ====================
__global__ __launch_bounds__(256) void k2_gc1_q(
    const int* __restrict__ startE, const int* __restrict__ elist,
    const float* __restrict__ xin,
    const float* wn, const float* wsf, const float* bias,
    const float* q_wi, const float* q_bi, const float* q_wh, const float* q_bh,
    const float* q_wo, const float* q_bo,
    float* __restrict__ x1_ws, float* __restrict__ out_f, float* __restrict__ jsf) {
  int tid = threadIdx.x, wv = tid >> 6, l = tid & 63;
  int d = blockIdx.x*4 + wv;
  __shared__ __align__(16) float bufA[4*100];
  __shared__ __align__(16) float bufB[4*100];
  __shared__ float smW[4*128];
  float* sm = smW + wv*128;
  // --- graph conv ---
  int p0 = startE[d], p1 = startE[d+1];
  float acc = 0.f;
  for (int p = p0; p < p1; ++p) acc += xin[elist[p]*64 + l];
  sm[l]      = acc / fmaxf((float)(p1 - p0), 1.0f);
  sm[64 + l] = xin[d*64 + l];
  __syncthreads();
  float o = bias[l];
  #pragma unroll 8
  for (int k = 0; k < 64; ++k)
    o += sm[k]*wn[k*64 + l] + sm[64 + k]*wsf[k*64 + l];
  x1_ws[d*64 + l] = o;
  out_f[d*64 + l] = o;
  bufA[wv*64 + l] = o;
  __syncthreads();
  // --- q MLP on the 4 fresh rows ---
  block_layer<64,100,4,true>(q_wi, q_bi, bufA, bufB, tid);
  block_layer<100,100,4,true>(q_wh, q_bh, bufB, bufA, tid);
  block_layer<100,100,4,true>(q_wh+10000, q_bh+100, bufA, bufB, tid);
  block_layer<100,18,4,false>(q_wo, q_bo, bufB, bufA, tid);
  int r0 = blockIdx.x*4;
  for (int o2 = tid; o2 < 4*18; o2 += 256) {
    int r = o2 / 18, c = o2 - r*18;
    jsf[(r0+r)*20 + c] = bufA[o2];
  }
}

// ==================== K3: pool_l2 + t2 MLP (4 clusters/block, 128 blocks) ====================
__global__ __launch_bounds__(256) void k3_pool_t2(
    const int* __restrict__ startc2, const int* __restrict__ r2list,
    const float* __restrict__ x1, const float* __restrict__ s1c_raw, const float* __restrict__ c1f,
    const float* t2_wi, const float* t2_bi, const float* t2_wh, const float* t2_bh,
    const float* t2_wo, const float* t2_bo,
    float* __restrict__ x2fc, float* __restrict__ jsf2) {
  int tid = threadIdx.x, wv = tid >> 6, l = tid & 63;
  int s2 = blockIdx.x*4 + wv;
  __shared__ __align__(16) float bufA[4*100];
  __shared__ __align__(16) float bufB[4*100];
  int p0 = startc2[s2], p1 = startc2[s2+1];
  int k = l & 3;
  float acc = 0.f, sc = 0.f, cnt = 0.f;
  for (int p = p0; p < p1; ++p) {
    int r = r2list[p];
    acc += x1[r*64 + l];
    sc  += s1c_raw[r*4 + k];
    cnt += c1f[r];
  }
  float invr = 1.0f / fmaxf((float)(p1 - p0), 1.0f);
  bufA[wv*68 + l] = acc * invr;
  if (l < 4) {
    float mean = sc / fmaxf(cnt, 1.0f);
    bufA[wv*68 + 64 + l] = mean;
    if (l == 0) jsf2[s2*20 + 18] = mean;
    if (l == 1) jsf2[s2*20 + 19] = mean;
  }
  __syncthreads();
  block_layer<68,100,4,true>(t2_wi, t2_bi, bufA, bufB, tid);
  block_layer<100,100,4,true>(t2_wh, t2_bh, bufB, bufA, tid);
  block_layer<100,100,4,true>(t2_wh+10000, t2_bh+100, bufA, bufB, tid);
  block_layer<100,64,4,false>(t2_wo, t2_bo, bufB, bufA, tid);
  int r0 = blockIdx.x*4;
  for (int o2 = tid; o2 < 4*64; o2 += 256) x2fc[r0*64 + o2] = bufA[o2];
}

// ==================== K4: gc2 + q-MLP(x2) (4 rows/block, 128 blocks) ====================
__global__ __launch_bounds__(256) void k4_gc2_q(
    const int* __restrict__ startE, const int* __restrict__ elist,
    const float* __restrict__ xin,
    const float* wn, const float* wsf, const float* bias,
    const float* q_wi, const float* q_bi, const float* q_wh, const float* q_bh,
    const float* q_wo, const float* q_bo,
    float* __restrict__ out_f, float* __restrict__ jsf2) {
  int tid = threadIdx.x, wv = tid >> 6, l = tid & 63;
  int d = blockIdx.x*4 + wv;
  __shared__ __align__(16) float bufA[4*100];
  __shared__ __align__(16) float bufB[4*100];
  __shared__ float smW[4*128];
  float* sm = smW + wv*128;
  int p0 = startE[d], p1 = startE[d+1];
  float acc = 0.f;
  for (int p = p0; p < p1; ++p) acc += xin[elist[p]*64 + l];
  sm[l]      = acc / fmaxf((float)(p1 - p0), 1.0f);
  sm[64 + l] = xin[d*64 + l];
  __syncthreads();
  float o = bias[l];
  #pragma unroll 8
  for (int k = 0; k < 64; ++k)
    o += sm[k]*wn[k*64 + l] + sm[64 + k]*wsf[k*64 + l];
  out_f[d*64 + l] = o;
  bufA[wv*64 + l] = o;
  __syncthreads();
  block_layer<64,100,4,true>(q_wi, q_bi, bufA, bufB, tid);
  block_layer<100,100,4,true>(q_wh, q_bh, bufB, bufA, tid);
  block_layer<100,100,4,true>(q_wh+10000, q_bh+100, bufA, bufB, tid);
  block_layer<100,18,4,false>(q_wo, q_bo, bufB, bufA, tid);
  int r0 = blockIdx.x*4;
  for (int o2 = tid; o2 < 4*18; o2 += 256) {
    int r = o2 / 18, c = o2 - r*18;
    jsf2[(r0+r)*20 + c] = bufA[o2];
  }
}

// ---------------- quadratic render (float4 jsf reads) ----------------
__global__ __launch_bounds__(256) void render_kernel(
    const int* __restrict__ cluster1, const int* __restrict__ cluster2,
    const float* __restrict__ jsf1, const float* __restrict__ jsf2,
    float* __restrict__ r1, float* __restrict__ r2) {
  int n = blockIdx.x*256 + threadIdx.x;
  int p = n & 65535, i = p >> 8, j = p & 255;
  float gy = i * (1.0f/256.0f), gx = j * (1.0f/256.0f);
  int s = cluster1[n];
  {
    const float4* f4 = reinterpret_cast<const float4*>(jsf1 + s*20);
    float4 v0 = f4[0], v1 = f4[1], v2 = f4[2], v3 = f4[3], v4 = f4[4];
    float dx = gy - v0.x, dy = gx - v0.y;
    float dxx = dx*dx, dyy = dy*dy, dxy = dx*dy;
    r1[n*3 + 0] = v0.z + v0.w*dx + v1.x*dy + v1.y*dxx + v1.z*dyy + v1.w*dxy;
    r1[n*3 + 1] = v2.x + v2.y*dx + v2.z*dy + v2.w*dxx + v3.x*dyy + v3.y*dxy;
    r1[n*3 + 2] = v3.z + v3.w*dx + v4.x*dy + v4.y*dxx + v4.z*dyy + v4.w*dxy;
  }
  int s2 = cluster2[s];
  {
    const float4* f4 = reinterpret_cast<const float4*>(jsf2 + s2*20);
    float4 v0 = f4[0], v1 = f4[1], v2 = f4[2], v3 = f4[3], v4 = f4[4];
    float dx = gy - v0.x, dy = gx - v0.y;
    float dxx = dx*dx, dyy = dy*dy, dxy = dx*dy;
    r2[n*3 + 0] = v0.z + v0.w*dx + v1.x*dy + v1.y*dxx + v1.z*dyy + v1.w*dxy;
    r2[n*3 + 1] = v2.x + v2.y*dx + v2.z*dy + v2.w*dxx + v3.x*dyy + v3.y*dxy;
    r2[n*3 + 2] = v3.z + v3.w*dx + v4.x*dy + v4.y*dxx + v4.z*dyy + v4.w*dxy;
  }
}

extern "C" void kernel_launch(void* const* d_in, const int* in_sizes, int n_in,
                              void* d_out, int out_size, void* d_ws, size_t ws_size,
                              hipStream_t stream) {
  const float* img    = (const float*)d_in[0];
  const float* conv_w = (const float*)d_in[1];
  const float* conv_b = (const float*)d_in[2];
  const float* t1_wi = (const float*)d_in[3];  const float* t1_bi = (const float*)d_in[4];
  const float* t1_wh = (const float*)d_in[5];  const float* t1_bh = (const float*)d_in[6];
  const float* t1_wo = (const float*)d_in[7];  const float* t1_bo = (const float*)d_in[8];
  const float* t2_wi = (const float*)d_in[9];  const float* t2_bi = (const float*)d_in[10];
  const float* t2_wh = (const float*)d_in[11]; const float* t2_bh = (const float*)d_in[12];
  const float* t2_wo = (const float*)d_in[13]; const float* t2_bo = (const float*)d_in[14];
  const float* q_wi  = (const float*)d_in[15]; const float* q_bi  = (const float*)d_in[16];
  const float* q_wh  = (const float*)d_in[17]; const float* q_bh  = (const float*)d_in[18];
  const float* q_wo  = (const float*)d_in[19]; const float* q_bo  = (const float*)d_in[20];
  const float* gc1_wn = (const float*)d_in[21]; const float* gc1_ws = (const float*)d_in[22];
  const float* gc1_b  = (const float*)d_in[23];
  const float* gc2_wn = (const float*)d_in[24]; const float* gc2_ws = (const float*)d_in[25];
  const float* gc2_b  = (const float*)d_in[26];
  const int* cluster1 = (const int*)d_in[27];
  const int* cluster2 = (const int*)d_in[28];
  const int* edges1   = (const int*)d_in[29];
  const int* edges2   = (const int*)d_in[30];

  float* ws = (float*)d_ws;
  int*   wsI = (int*)d_ws;
  float* out  = (float*)d_out;
  float* o_r1 = out;
  float* o_r2 = out + 786432;
  float* o_x1 = out + 1572864;
  float* o_x2 = out + 1835008;

  // zero only the int histograms (36 KB)
  hipMemsetAsync(d_ws, 0, (size_t)ZEROI_END * sizeof(int), stream);

  constexpr int TOTW = NPIX + M1C + E1C + E2C;   // 339968, /256 = 1328 exact
  build_hist<<<TOTW/256, 256, 0, stream>>>(cluster1, cluster2, edges1, edges2, wsI);
  scan_kernel<<<4, 1024, 0, stream>>>(wsI);
  scatter_all<<<TOTW/256, 256, 0, stream>>>(cluster1, cluster2, edges1, edges2, wsI);

  // K1: conv-linearity gather + t1 MLP (x1cat never hits global)
  k1_gather_t1<<<M1C/4, 256, 0, stream>>>(img, conv_w, conv_b,
      wsI+IOFF_ST1, wsI+IOFF_PLIST,
      t1_wi, t1_bi, t1_wh, t1_bh, t1_wo, t1_bo,
      ws+OFF_X1FC, ws+OFF_S1CR, ws+OFF_C1, ws+OFF_JSF1);

  // K2: graph conv 1 + q MLP on x1 rows
  k2_gc1_q<<<M1C/4, 256, 0, stream>>>(wsI+IOFF_STE1, wsI+IOFF_E1L, ws+OFF_X1FC,
      gc1_wn, gc1_ws, gc1_b,
      q_wi, q_bi, q_wh, q_bh, q_wo, q_bo,
      ws+OFF_X1, o_x1, ws+OFF_JSF1);

  // K3: level-2 pooling + t2 MLP
  k3_pool_t2<<<M2C/4, 256, 0, stream>>>(wsI+IOFF_STC2, wsI+IOFF_R2L,
      ws+OFF_X1, ws+OFF_S1CR, ws+OFF_C1,
      t2_wi, t2_bi, t2_wh, t2_bh, t2_wo, t2_bo,
      ws+OFF_X2FC, ws+OFF_JSF2);

  // K4: graph conv 2 + q MLP on x2 rows
  k4_gc2_q<<<M2C/4, 256, 0, stream>>>(wsI+IOFF_STE2, wsI+IOFF_E2L, ws+OFF_X2FC,
      gc2_wn, gc2_ws, gc2_b,
      q_wi, q_bi, q_wh, q_bh, q_wo, q_bo,
      o_x2, ws+OFF_JSF2);

  // render
  render_kernel<<<NPIX/256, 256, 0, stream>>>(cluster1, cluster2, ws+OFF_JSF1, ws+OFF_JSF2, o_r1, o_r2);
}